// Round 1
// baseline (139.853 us; speedup 1.0000x reference)
//
#include <hip/hip_runtime.h>
#include <stdint.h>

typedef __bf16 bf16x8 __attribute__((ext_vector_type(8)));
typedef float  f32x4  __attribute__((ext_vector_type(4)));

#define E_DIM 1024
#define H_DIM 64
#define T_SEQ 4096
#define B_BAT 4
#define M_TOT (B_BAT * T_SEQ)   // 16384
#define NSPLIT 8                 // key splits (was 4): 1024 blocks -> 4 blocks/CU

__device__ __forceinline__ uint32_t f2bf1(float f) {
    uint32_t u = __float_as_uint(f);
    return (u + 0x7FFFu + ((u >> 16) & 1u)) >> 16;
}
// packed fp32x2 -> bf16x2 (RNE)
__device__ __forceinline__ uint32_t pk2(float lo, float hi) {
    return f2bf1(lo) | (f2bf1(hi) << 16);
}
__device__ __forceinline__ bf16x8 ldfrag(const ushort* p) {
    return __builtin_bit_cast(bf16x8, *(const uint4*)(p));
}
// barrier that waits LDS only — global prefetch stays in flight (vmcnt not drained)
__device__ __forceinline__ void barrier_lgkm() {
    __builtin_amdgcn_s_waitcnt(0xC07F);   // vmcnt(63) expcnt(7) lgkmcnt(0)
    __builtin_amdgcn_s_barrier();
}

// ---------------- kernel 0: W fp32 -> frag-major bf16 -----------------------
// Wfm[s 16][nt 12][kc 2][lane 64][8]; Wq rows (n<64) pre-scaled by 1/32.
__global__ __launch_bounds__(256) void wcvt(const float* __restrict__ Wq,
                                            const float* __restrict__ Wk,
                                            const float* __restrict__ Wv,
                                            ushort* __restrict__ Wfm) {
    int g = blockIdx.x * 256 + threadIdx.x;   // 24576 threads
    int n = g >> 7;          // 0..191
    int k8 = g & 127;
    const float* src = (n < 64) ? (Wq + (size_t)n * E_DIM)
                     : (n < 128) ? (Wk + (size_t)(n - 64) * E_DIM)
                     : (Wv + (size_t)(n - 128) * E_DIM);
    float sc = (n < 64) ? 0.03125f : 1.0f;
    float4 a = *(const float4*)(src + k8 * 8);
    float4 b = *(const float4*)(src + k8 * 8 + 4);
    uint4 o;
    o.x = pk2(a.x * sc, a.y * sc); o.y = pk2(a.z * sc, a.w * sc);
    o.z = pk2(b.x * sc, b.y * sc); o.w = pk2(b.z * sc, b.w * sc);
    int s = k8 >> 3, kc = (k8 >> 2) & 1, qd = k8 & 3;
    int nt = n >> 4, lm = n & 15;
    int lane = qd * 16 + lm;
    *(uint4*)(Wfm + (((size_t)(s * 12 + nt) * 2 + kc) * 64 + lane) * 8) = o;
}

// ---------------- kernel 1: QKV projection ----------------------------------
// 32-row blocks, BK=64, 16 steps. 2-deep x pipeline (load s+2 / stage s+1 /
// compute s); lgkm-only in-loop barriers keep global loads in flight.
__global__ __launch_bounds__(256, 3) void qkv(const float* __restrict__ x,
                                              const ushort* __restrict__ Wfm,
                                              ushort* __restrict__ Qfm,
                                              ushort* __restrict__ Kfm,
                                              ushort* __restrict__ Vfm) {
    __shared__ union {
        ushort a[2][32 * 72];                              // staging dbuf (9216 B)
        struct { ushort c[32 * 136]; ushort vt[64 * 40]; } epi;  // epilogue (13824 B)
    } sm;
    const int tid = threadIdx.x;
    const int w = tid >> 6, l = tid & 63;
    const int lm = l & 15, qd = l >> 4;
    const int m0 = blockIdx.x * 32;

    f32x4 acc[2][3];
#pragma unroll
    for (int r2 = 0; r2 < 2; ++r2)
#pragma unroll
        for (int t = 0; t < 3; ++t) acc[r2][t] = (f32x4){0.f, 0.f, 0.f, 0.f};

    const int srow = tid >> 3, kseg = tid & 7;
    const float* xsrc = x + (size_t)(m0 + srow) * E_DIM + kseg * 8;

    // tile 0 -> LDS[0]
    {
        float4 a0 = *(const float4*)xsrc;
        float4 a1 = *(const float4*)(xsrc + 4);
        uint4 u = {pk2(a0.x, a0.y), pk2(a0.z, a0.w), pk2(a1.x, a1.y), pk2(a1.z, a1.w)};
        *(uint4*)(&sm.a[0][srow * 72 + kseg * 8]) = u;
    }
    // tile 1 -> regs
    float4 xn0 = *(const float4*)(xsrc + 64);
    float4 xn1 = *(const float4*)(xsrc + 68);
    __syncthreads();

    for (int s = 0; s < 16; ++s) {
        const int cb = s & 1, nb = cb ^ 1;
        float4 x20 = xn0, x21 = xn1;
        if (s < 14) {                       // load tile s+2
            x20 = *(const float4*)(xsrc + (s + 2) * 64);
            x21 = *(const float4*)(xsrc + (s + 2) * 64 + 4);
        }
        // W frags for this step (global, L2-resident, lane-dense)
        bf16x8 wf[3][2];
#pragma unroll
        for (int t = 0; t < 3; ++t)
#pragma unroll
            for (int kc = 0; kc < 2; ++kc)
                wf[t][kc] = ldfrag(Wfm + (((size_t)(s * 12 + w * 3 + t) * 2 + kc) * 64 + l) * 8);
        // A frags from LDS
        bf16x8 af[2][2];
#pragma unroll
        for (int r2 = 0; r2 < 2; ++r2)
#pragma unroll
            for (int kc = 0; kc < 2; ++kc)
                af[r2][kc] = ldfrag(&sm.a[cb][(r2 * 16 + lm) * 72 + kc * 32 + qd * 8]);
#pragma unroll
        for (int t = 0; t < 3; ++t)
#pragma unroll
            for (int kc = 0; kc < 2; ++kc)
#pragma unroll
                for (int r2 = 0; r2 < 2; ++r2)
                    acc[r2][t] = __builtin_amdgcn_mfma_f32_16x16x32_bf16(af[r2][kc], wf[t][kc], acc[r2][t], 0, 0, 0);
        // stage tile s+1 (regs loaded one full step ago)
        if (s < 15) {
            uint4 u = {pk2(xn0.x, xn0.y), pk2(xn0.z, xn0.w), pk2(xn1.x, xn1.y), pk2(xn1.z, xn1.w)};
            *(uint4*)(&sm.a[nb][srow * 72 + kseg * 8]) = u;
        }
        xn0 = x20; xn1 = x21;
        if (s < 15) barrier_lgkm();
    }
    __syncthreads();

    // epilogue: acc -> LDS transpose -> frag-major dense stores
#pragma unroll
    for (int r2 = 0; r2 < 2; ++r2)
#pragma unroll
        for (int t = 0; t < 3; ++t) {
            int gc = w * 48 + t * 16 + lm;
            int m = r2 * 16 + qd * 4;
#pragma unroll
            for (int rr = 0; rr < 4; ++rr) {
                ushort v = (ushort)f2bf1(acc[r2][t][rr]);
                if (gc < 128) sm.epi.c[(m + rr) * 136 + gc] = v;
                else          sm.epi.vt[(gc - 128) * 40 + (m + rr)] = v;
            }
        }
    __syncthreads();

    const int g16b = m0 >> 4;
    const int kt64 = m0 >> 6;
    const int tb   = (m0 >> 4) & 3;
    const int kcv  = (m0 >> 5) & 1;
#pragma unroll
    for (int ii = 0; ii < 3; ++ii) {
        int i = w + ii * 4;
        uint4 val;
        ushort* dst;
        if (i < 4) {
            int qt_l = i >> 1, kc = i & 1;
            val = *(const uint4*)(&sm.epi.c[(qt_l * 16 + lm) * 136 + kc * 32 + qd * 8]);
            dst = Qfm + (((size_t)(g16b + qt_l) * 2 + kc) * 64 + l) * 8;
        } else if (i < 8) {
            int j2 = i - 4, t_l = j2 >> 1, kc = j2 & 1;
            val = *(const uint4*)(&sm.epi.c[(t_l * 16 + lm) * 136 + 64 + kc * 32 + qd * 8]);
            dst = Kfm + (((size_t)((kt64 * 4 + tb + t_l) * 2 + kc)) * 64 + l) * 8;
        } else {
            int t = i - 8;
            val = *(const uint4*)(&sm.epi.vt[(t * 16 + lm) * 40 + qd * 8]);
            dst = Vfm + (((size_t)((kt64 * 4 + t) * 2 + kcv)) * 64 + l) * 8;
        }
        *(uint4*)dst = val;
    }
}

// ---------------- kernel 2: causal flash attention --------------------------
// S^T = K·Q^T; pair-balanced (p, 63-p); split-8 keys across blocks; mask only
// the diagonal tile; packed b64 P writes; wave-private P LDS (no block barriers).
// Split-8: 1024 blocks -> 4 blocks/CU = 4 waves/SIMD (fills launch_bounds),
// doubling the latency-hiding pool for the serial S->exp->LDS->PV chain.
__global__ __launch_bounds__(256, 4) void flash(const ushort* __restrict__ Qfm,
                                                const ushort* __restrict__ Kfm,
                                                const ushort* __restrict__ Vfm,
                                                float* __restrict__ Opart,
                                                float* __restrict__ lpart) {
    __shared__ ushort plds[4][16 * 72];  // stride 72: odd 16B-slot stride -> bank-uniform
    const int tid = threadIdx.x;
    const int wv = tid >> 6, l = tid & 63;
    const int lm = l & 15, qd = l >> 4;
    const int pr = blockIdx.x;   // pair 0..31
    const int bt = blockIdx.y;
    const int h  = blockIdx.z;   // key split 0..7
    ushort* myp = plds[wv];

#pragma unroll 1
    for (int half = 0; half < 2; ++half) {
        const int qt = half ? (63 - pr) : pr;
        const size_t rowg = (size_t)bt * T_SEQ + qt * 64 + wv * 16;
        const int g16 = bt * 256 + qt * 4 + wv;

        bf16x8 qf0, qf1;
        {
            const ushort* qp = Qfm + ((size_t)g16 * 2) * 512 + l * 8;
            qf0 = ldfrag(qp);
            qf1 = ldfrag(qp + 512);
        }
        f32x4 o[4];
#pragma unroll
        for (int t = 0; t < 4; ++t) o[t] = (f32x4){0.f, 0.f, 0.f, 0.f};
        float lacc = 0.f;

#pragma unroll 1
        for (int kt = h; kt <= qt; kt += NSPLIT) {
            const ushort* kb = Kfm + ((size_t)(bt * 64 + kt) * 8) * 512;
            const ushort* vb = Vfm + ((size_t)(bt * 64 + kt) * 8) * 512;
            f32x4 sf[4];
#pragma unroll
            for (int t = 0; t < 4; ++t) sf[t] = (f32x4){0.f, 0.f, 0.f, 0.f};
#pragma unroll
            for (int t = 0; t < 4; ++t) {
                bf16x8 k0 = ldfrag(kb + (t * 2 + 0) * 512 + l * 8);
                bf16x8 k1 = ldfrag(kb + (t * 2 + 1) * 512 + l * 8);
                sf[t] = __builtin_amdgcn_mfma_f32_16x16x32_bf16(k0, qf0, sf[t], 0, 0, 0);
                sf[t] = __builtin_amdgcn_mfma_f32_16x16x32_bf16(k1, qf1, sf[t], 0, 0, 0);
            }
            uint4 vu[4][2];
#pragma unroll
            for (int t = 0; t < 4; ++t) {
                vu[t][0] = *(const uint4*)(vb + (t * 2 + 0) * 512 + l * 8);
                vu[t][1] = *(const uint4*)(vb + (t * 2 + 1) * 512 + l * 8);
            }
            ushort* wp = myp + lm * 72 + qd * 4;
            if (kt != qt) {            // fully unmasked tile
#pragma unroll
                for (int t = 0; t < 4; ++t) {
                    float p0 = __expf(sf[t][0]), p1 = __expf(sf[t][1]);
                    float p2 = __expf(sf[t][2]), p3 = __expf(sf[t][3]);
                    lacc += (p0 + p1) + (p2 + p3);
                    *(uint2*)(wp + t * 16) = uint2{pk2(p0, p1), pk2(p2, p3)};
                }
            } else {                   // diagonal tile: t<wv full, t==wv tri, t>wv zero
#pragma unroll
                for (int t = 0; t < 4; ++t) {
                    if (t < wv) {
                        float p0 = __expf(sf[t][0]), p1 = __expf(sf[t][1]);
                        float p2 = __expf(sf[t][2]), p3 = __expf(sf[t][3]);
                        lacc += (p0 + p1) + (p2 + p3);
                        *(uint2*)(wp + t * 16) = uint2{pk2(p0, p1), pk2(p2, p3)};
                    } else if (t == wv) {
                        float p[4];
#pragma unroll
                        for (int rr = 0; rr < 4; ++rr) {
                            float pe = __expf(sf[t][rr]);
                            if (qd * 4 + rr > lm) pe = 0.f;
                            lacc += pe;
                            p[rr] = pe;
                        }
                        *(uint2*)(wp + t * 16) = uint2{pk2(p[0], p[1]), pk2(p[2], p[3])};
                    } else {
                        *(uint2*)(wp + t * 16) = uint2{0u, 0u};
                    }
                }
            }
            __builtin_amdgcn_wave_barrier();
            __builtin_amdgcn_s_waitcnt(0xC07F);  // lgkmcnt(0): P committed (wave-private)
            __builtin_amdgcn_wave_barrier();
            bf16x8 pf0 = ldfrag(myp + lm * 72 + qd * 8);
            bf16x8 pf1 = ldfrag(myp + lm * 72 + 32 + qd * 8);
#pragma unroll
            for (int t = 0; t < 4; ++t) {
                bf16x8 v0 = __builtin_bit_cast(bf16x8, vu[t][0]);
                bf16x8 v1 = __builtin_bit_cast(bf16x8, vu[t][1]);
                o[t] = __builtin_amdgcn_mfma_f32_16x16x32_bf16(pf0, v0, o[t], 0, 0, 0);
                o[t] = __builtin_amdgcn_mfma_f32_16x16x32_bf16(pf1, v1, o[t], 0, 0, 0);
            }
            __builtin_amdgcn_wave_barrier();  // next iter's P writes stay after these reads
        }
        lacc += __shfl_xor(lacc, 16);
        lacc += __shfl_xor(lacc, 32);

        float* ob = Opart + ((size_t)h * M_TOT + rowg) * 64;
#pragma unroll
        for (int t = 0; t < 4; ++t)
#pragma unroll
            for (int rr = 0; rr < 4; ++rr)
                ob[(size_t)(qd * 4 + rr) * 64 + t * 16 + lm] = o[t][rr];
        if (qd == 0) lpart[(size_t)h * M_TOT + rowg + lm] = lacc;
    }
}

// ---------------- kernel 3: combine split-8 partials ------------------------
__global__ __launch_bounds__(256) void combine(const float* __restrict__ Opart,
                                               const float* __restrict__ lpart,
                                               float* __restrict__ out) {
    int i4 = blockIdx.x * 256 + threadIdx.x;   // 262144 float4s
    size_t base = (size_t)i4 * 4;
    int row = i4 >> 4;
    float ls = 0.f;
#pragma unroll
    for (int s = 0; s < NSPLIT; ++s) ls += lpart[(size_t)s * M_TOT + row];
    const size_t SP = (size_t)M_TOT * 64;
    float4 o = {0.f, 0.f, 0.f, 0.f};
#pragma unroll
    for (int s = 0; s < NSPLIT; ++s) {
        float4 a = *(const float4*)(Opart + (size_t)s * SP + base);
        o.x += a.x; o.y += a.y; o.z += a.z; o.w += a.w;
    }
    float inv = 1.0f / ls;
    o.x *= inv; o.y *= inv; o.z *= inv; o.w *= inv;
    *(float4*)(out + base) = o;
}

extern "C" void kernel_launch(void* const* d_in, const int* in_sizes, int n_in,
                              void* d_out, int out_size, void* d_ws, size_t ws_size,
                              hipStream_t stream) {
    const float* x  = (const float*)d_in[0];
    const float* Wq = (const float*)d_in[1];
    const float* Wk = (const float*)d_in[2];
    const float* Wv = (const float*)d_in[3];
    float* out = (float*)d_out;

    char* ws = (char*)d_ws;
    ushort* Wfm = (ushort*)(ws);                 // 384 KB
    ushort* Qfm = (ushort*)(ws + 393216);        // 2 MB
    ushort* Kfm = (ushort*)(ws + 2490368);       // 2 MB
    ushort* Vfm = (ushort*)(ws + 4587520);       // 2 MB
    float*  Op  = (float*) (ws + 6684672);       // 32 MB (8 splits x 4 MB)
    float*  lp  = (float*) (ws + 6684672 + (size_t)NSPLIT * M_TOT * 64 * 4);  // 512 KB

    wcvt<<<96, 256, 0, stream>>>(Wq, Wk, Wv, Wfm);
    qkv<<<512, 256, 0, stream>>>(x, Wfm, Qfm, Kfm, Vfm);
    flash<<<dim3(32, B_BAT, NSPLIT), 256, 0, stream>>>(Qfm, Kfm, Vfm, Op, lp);
    combine<<<1024, 256, 0, stream>>>(Op, lp, out);
}

// Round 2
// 135.210 us; speedup vs baseline: 1.0343x; 1.0343x over previous
//
#include <hip/hip_runtime.h>
#include <stdint.h>

typedef __bf16 bf16x8 __attribute__((ext_vector_type(8)));
typedef float  f32x4  __attribute__((ext_vector_type(4)));

#define E_DIM 1024
#define H_DIM 64
#define T_SEQ 4096
#define B_BAT 4
#define M_TOT (B_BAT * T_SEQ)   // 16384
#define NSPLIT 4                 // key splits (8 regressed: flash not wave-starved)

// f32 -> bf16 via hardware cvt (RNE, v_cvt_pk_bf16_f32). Compiler pairs casts.
__device__ __forceinline__ ushort f2bfu(float f) {
    return __builtin_bit_cast(ushort, (__bf16)f);
}
// packed fp32x2 -> bf16x2 (RNE, single v_cvt_pk_bf16_f32)
__device__ __forceinline__ uint32_t pk2(float lo, float hi) {
    return (uint32_t)f2bfu(lo) | ((uint32_t)f2bfu(hi) << 16);
}
__device__ __forceinline__ float ex2(float x) {    // 2^x, single trans op
    return __builtin_amdgcn_exp2f(x);
}
__device__ __forceinline__ bf16x8 ldfrag(const ushort* p) {
    return __builtin_bit_cast(bf16x8, *(const uint4*)(p));
}
// barrier that waits LDS only — global prefetch stays in flight (vmcnt not drained)
__device__ __forceinline__ void barrier_lgkm() {
    __builtin_amdgcn_s_waitcnt(0xC07F);   // vmcnt(63) expcnt(7) lgkmcnt(0)
    __builtin_amdgcn_s_barrier();
}

// ---------------- kernel 0: W fp32 -> frag-major bf16 -----------------------
// Wfm[s 16][nt 12][kc 2][lane 64][8]; Wq rows (n<64) pre-scaled by 1/(32*ln2)
// so flash can use exp2 directly (softmax invariant to the log-base change).
__global__ __launch_bounds__(256) void wcvt(const float* __restrict__ Wq,
                                            const float* __restrict__ Wk,
                                            const float* __restrict__ Wv,
                                            ushort* __restrict__ Wfm) {
    int g = blockIdx.x * 256 + threadIdx.x;   // 24576 threads
    int n = g >> 7;          // 0..191
    int k8 = g & 127;
    const float* src = (n < 64) ? (Wq + (size_t)n * E_DIM)
                     : (n < 128) ? (Wk + (size_t)(n - 64) * E_DIM)
                     : (Wv + (size_t)(n - 128) * E_DIM);
    float sc = (n < 64) ? 0.045084220f : 1.0f;   // (1/32) * (1/ln2)
    float4 a = *(const float4*)(src + k8 * 8);
    float4 b = *(const float4*)(src + k8 * 8 + 4);
    uint4 o;
    o.x = pk2(a.x * sc, a.y * sc); o.y = pk2(a.z * sc, a.w * sc);
    o.z = pk2(b.x * sc, b.y * sc); o.w = pk2(b.z * sc, b.w * sc);
    int s = k8 >> 3, kc = (k8 >> 2) & 1, qd = k8 & 3;
    int nt = n >> 4, lm = n & 15;
    int lane = qd * 16 + lm;
    *(uint4*)(Wfm + (((size_t)(s * 12 + nt) * 2 + kc) * 64 + lane) * 8) = o;
}

// ---------------- kernel 1: QKV projection ----------------------------------
// 32-row blocks, BK=64, 16 steps. 3-deep x pipeline (load s+3 / stage s+1 /
// compute s) — ~2.3 steps of HBM-latency cover at the stage point;
// lgkm-only in-loop barriers keep global loads in flight.
__global__ __launch_bounds__(256, 3) void qkv(const float* __restrict__ x,
                                              const ushort* __restrict__ Wfm,
                                              ushort* __restrict__ Qfm,
                                              ushort* __restrict__ Kfm,
                                              ushort* __restrict__ Vfm) {
    __shared__ union {
        ushort a[2][32 * 72];                              // staging dbuf (9216 B)
        struct { ushort c[32 * 136]; ushort vt[64 * 40]; } epi;  // epilogue (13824 B)
    } sm;
    const int tid = threadIdx.x;
    const int w = tid >> 6, l = tid & 63;
    const int lm = l & 15, qd = l >> 4;
    const int m0 = blockIdx.x * 32;

    f32x4 acc[2][3];
#pragma unroll
    for (int r2 = 0; r2 < 2; ++r2)
#pragma unroll
        for (int t = 0; t < 3; ++t) acc[r2][t] = (f32x4){0.f, 0.f, 0.f, 0.f};

    const int srow = tid >> 3, kseg = tid & 7;
    const float* xsrc = x + (size_t)(m0 + srow) * E_DIM + kseg * 8;

    // tile 0 -> LDS[0]
    {
        float4 a0 = *(const float4*)xsrc;
        float4 a1 = *(const float4*)(xsrc + 4);
        uint4 u = {pk2(a0.x, a0.y), pk2(a0.z, a0.w), pk2(a1.x, a1.y), pk2(a1.z, a1.w)};
        *(uint4*)(&sm.a[0][srow * 72 + kseg * 8]) = u;
    }
    // tiles 1,2 -> regs (3-deep pipeline)
    float4 xa0 = *(const float4*)(xsrc + 64);
    float4 xa1 = *(const float4*)(xsrc + 68);
    float4 xb0 = *(const float4*)(xsrc + 128);
    float4 xb1 = *(const float4*)(xsrc + 132);
    __syncthreads();

    for (int s = 0; s < 16; ++s) {
        const int cb = s & 1, nb = cb ^ 1;
        float4 xc0 = xa0, xc1 = xa1;
        if (s < 13) {                       // load tile s+3
            xc0 = *(const float4*)(xsrc + (s + 3) * 64);
            xc1 = *(const float4*)(xsrc + (s + 3) * 64 + 4);
        }
        // W frags for this step (global, L2-resident, lane-dense)
        bf16x8 wf[3][2];
#pragma unroll
        for (int t = 0; t < 3; ++t)
#pragma unroll
            for (int kc = 0; kc < 2; ++kc)
                wf[t][kc] = ldfrag(Wfm + (((size_t)(s * 12 + w * 3 + t) * 2 + kc) * 64 + l) * 8);
        // A frags from LDS
        bf16x8 af[2][2];
#pragma unroll
        for (int r2 = 0; r2 < 2; ++r2)
#pragma unroll
            for (int kc = 0; kc < 2; ++kc)
                af[r2][kc] = ldfrag(&sm.a[cb][(r2 * 16 + lm) * 72 + kc * 32 + qd * 8]);
#pragma unroll
        for (int t = 0; t < 3; ++t)
#pragma unroll
            for (int kc = 0; kc < 2; ++kc)
#pragma unroll
                for (int r2 = 0; r2 < 2; ++r2)
                    acc[r2][t] = __builtin_amdgcn_mfma_f32_16x16x32_bf16(af[r2][kc], wf[t][kc], acc[r2][t], 0, 0, 0);
        // stage tile s+1 (regs loaded two full steps ago)
        if (s < 15) {
            uint4 u = {pk2(xa0.x, xa0.y), pk2(xa0.z, xa0.w), pk2(xa1.x, xa1.y), pk2(xa1.z, xa1.w)};
            *(uint4*)(&sm.a[nb][srow * 72 + kseg * 8]) = u;
        }
        xa0 = xb0; xa1 = xb1; xb0 = xc0; xb1 = xc1;
        if (s < 15) barrier_lgkm();
    }
    __syncthreads();

    // epilogue: acc -> LDS transpose -> frag-major dense stores
#pragma unroll
    for (int r2 = 0; r2 < 2; ++r2)
#pragma unroll
        for (int t = 0; t < 3; ++t) {
            int gc = w * 48 + t * 16 + lm;
            int m = r2 * 16 + qd * 4;
#pragma unroll
            for (int rr = 0; rr < 4; ++rr) {
                ushort v = f2bfu(acc[r2][t][rr]);
                if (gc < 128) sm.epi.c[(m + rr) * 136 + gc] = v;
                else          sm.epi.vt[(gc - 128) * 40 + (m + rr)] = v;
            }
        }
    __syncthreads();

    const int g16b = m0 >> 4;
    const int kt64 = m0 >> 6;
    const int tb   = (m0 >> 4) & 3;
    const int kcv  = (m0 >> 5) & 1;
#pragma unroll
    for (int ii = 0; ii < 3; ++ii) {
        int i = w + ii * 4;
        uint4 val;
        ushort* dst;
        if (i < 4) {
            int qt_l = i >> 1, kc = i & 1;
            val = *(const uint4*)(&sm.epi.c[(qt_l * 16 + lm) * 136 + kc * 32 + qd * 8]);
            dst = Qfm + (((size_t)(g16b + qt_l) * 2 + kc) * 64 + l) * 8;
        } else if (i < 8) {
            int j2 = i - 4, t_l = j2 >> 1, kc = j2 & 1;
            val = *(const uint4*)(&sm.epi.c[(t_l * 16 + lm) * 136 + 64 + kc * 32 + qd * 8]);
            dst = Kfm + (((size_t)((kt64 * 4 + tb + t_l) * 2 + kc)) * 64 + l) * 8;
        } else {
            int t = i - 8;
            val = *(const uint4*)(&sm.epi.vt[(t * 16 + lm) * 40 + qd * 8]);
            dst = Vfm + (((size_t)((kt64 * 4 + t) * 2 + kcv)) * 64 + l) * 8;
        }
        *(uint4*)dst = val;
    }
}

// ---------------- kernel 2: causal flash attention --------------------------
// S^T = K·Q^T; pair-balanced (p, 63-p); split-4 keys across blocks; mask only
// the diagonal tile; packed b64 P writes; wave-private P LDS (no block barriers).
// exp2-direct: 1/ln2 folded into Wq pre-scale, single v_exp_f32 per element.
__global__ __launch_bounds__(256, 4) void flash(const ushort* __restrict__ Qfm,
                                                const ushort* __restrict__ Kfm,
                                                const ushort* __restrict__ Vfm,
                                                float* __restrict__ Opart,
                                                float* __restrict__ lpart) {
    __shared__ ushort plds[4][16 * 72];  // stride 72: odd 16B-slot stride -> bank-uniform
    const int tid = threadIdx.x;
    const int wv = tid >> 6, l = tid & 63;
    const int lm = l & 15, qd = l >> 4;
    const int pr = blockIdx.x;   // pair 0..31
    const int bt = blockIdx.y;
    const int h  = blockIdx.z;   // key split 0..3
    ushort* myp = plds[wv];

#pragma unroll 1
    for (int half = 0; half < 2; ++half) {
        const int qt = half ? (63 - pr) : pr;
        const size_t rowg = (size_t)bt * T_SEQ + qt * 64 + wv * 16;
        const int g16 = bt * 256 + qt * 4 + wv;

        bf16x8 qf0, qf1;
        {
            const ushort* qp = Qfm + ((size_t)g16 * 2) * 512 + l * 8;
            qf0 = ldfrag(qp);
            qf1 = ldfrag(qp + 512);
        }
        f32x4 o[4];
#pragma unroll
        for (int t = 0; t < 4; ++t) o[t] = (f32x4){0.f, 0.f, 0.f, 0.f};
        float lacc = 0.f;

#pragma unroll 1
        for (int kt = h; kt <= qt; kt += NSPLIT) {
            const ushort* kb = Kfm + ((size_t)(bt * 64 + kt) * 8) * 512;
            const ushort* vb = Vfm + ((size_t)(bt * 64 + kt) * 8) * 512;
            f32x4 sf[4];
#pragma unroll
            for (int t = 0; t < 4; ++t) sf[t] = (f32x4){0.f, 0.f, 0.f, 0.f};
#pragma unroll
            for (int t = 0; t < 4; ++t) {
                bf16x8 k0 = ldfrag(kb + (t * 2 + 0) * 512 + l * 8);
                bf16x8 k1 = ldfrag(kb + (t * 2 + 1) * 512 + l * 8);
                sf[t] = __builtin_amdgcn_mfma_f32_16x16x32_bf16(k0, qf0, sf[t], 0, 0, 0);
                sf[t] = __builtin_amdgcn_mfma_f32_16x16x32_bf16(k1, qf1, sf[t], 0, 0, 0);
            }
            uint4 vu[4][2];
#pragma unroll
            for (int t = 0; t < 4; ++t) {
                vu[t][0] = *(const uint4*)(vb + (t * 2 + 0) * 512 + l * 8);
                vu[t][1] = *(const uint4*)(vb + (t * 2 + 1) * 512 + l * 8);
            }
            ushort* wp = myp + lm * 72 + qd * 4;
            if (kt != qt) {            // fully unmasked tile
#pragma unroll
                for (int t = 0; t < 4; ++t) {
                    float p0 = ex2(sf[t][0]), p1 = ex2(sf[t][1]);
                    float p2 = ex2(sf[t][2]), p3 = ex2(sf[t][3]);
                    lacc += (p0 + p1) + (p2 + p3);
                    *(uint2*)(wp + t * 16) = uint2{pk2(p0, p1), pk2(p2, p3)};
                }
            } else {                   // diagonal tile: t<wv full, t==wv tri, t>wv zero
#pragma unroll
                for (int t = 0; t < 4; ++t) {
                    if (t < wv) {
                        float p0 = ex2(sf[t][0]), p1 = ex2(sf[t][1]);
                        float p2 = ex2(sf[t][2]), p3 = ex2(sf[t][3]);
                        lacc += (p0 + p1) + (p2 + p3);
                        *(uint2*)(wp + t * 16) = uint2{pk2(p0, p1), pk2(p2, p3)};
                    } else if (t == wv) {
                        float p[4];
#pragma unroll
                        for (int rr = 0; rr < 4; ++rr) {
                            float pe = ex2(sf[t][rr]);
                            if (qd * 4 + rr > lm) pe = 0.f;
                            lacc += pe;
                            p[rr] = pe;
                        }
                        *(uint2*)(wp + t * 16) = uint2{pk2(p[0], p[1]), pk2(p[2], p[3])};
                    } else {
                        *(uint2*)(wp + t * 16) = uint2{0u, 0u};
                    }
                }
            }
            __builtin_amdgcn_wave_barrier();
            __builtin_amdgcn_s_waitcnt(0xC07F);  // lgkmcnt(0): P committed (wave-private)
            __builtin_amdgcn_wave_barrier();
            bf16x8 pf0 = ldfrag(myp + lm * 72 + qd * 8);
            bf16x8 pf1 = ldfrag(myp + lm * 72 + 32 + qd * 8);
#pragma unroll
            for (int t = 0; t < 4; ++t) {
                bf16x8 v0 = __builtin_bit_cast(bf16x8, vu[t][0]);
                bf16x8 v1 = __builtin_bit_cast(bf16x8, vu[t][1]);
                o[t] = __builtin_amdgcn_mfma_f32_16x16x32_bf16(pf0, v0, o[t], 0, 0, 0);
                o[t] = __builtin_amdgcn_mfma_f32_16x16x32_bf16(pf1, v1, o[t], 0, 0, 0);
            }
            __builtin_amdgcn_wave_barrier();  // next iter's P writes stay after these reads
        }
        lacc += __shfl_xor(lacc, 16);
        lacc += __shfl_xor(lacc, 32);

        float* ob = Opart + ((size_t)h * M_TOT + rowg) * 64;
#pragma unroll
        for (int t = 0; t < 4; ++t)
#pragma unroll
            for (int rr = 0; rr < 4; ++rr)
                ob[(size_t)(qd * 4 + rr) * 64 + t * 16 + lm] = o[t][rr];
        if (qd == 0) lpart[(size_t)h * M_TOT + rowg + lm] = lacc;
    }
}

// ---------------- kernel 3: combine split partials --------------------------
__global__ __launch_bounds__(256) void combine(const float* __restrict__ Opart,
                                               const float* __restrict__ lpart,
                                               float* __restrict__ out) {
    int i4 = blockIdx.x * 256 + threadIdx.x;   // 262144 float4s
    size_t base = (size_t)i4 * 4;
    int row = i4 >> 4;
    float ls = 0.f;
#pragma unroll
    for (int s = 0; s < NSPLIT; ++s) ls += lpart[(size_t)s * M_TOT + row];
    const size_t SP = (size_t)M_TOT * 64;
    float4 o = {0.f, 0.f, 0.f, 0.f};
#pragma unroll
    for (int s = 0; s < NSPLIT; ++s) {
        float4 a = *(const float4*)(Opart + (size_t)s * SP + base);
        o.x += a.x; o.y += a.y; o.z += a.z; o.w += a.w;
    }
    float inv = 1.0f / ls;
    o.x *= inv; o.y *= inv; o.z *= inv; o.w *= inv;
    *(float4*)(out + base) = o;
}

extern "C" void kernel_launch(void* const* d_in, const int* in_sizes, int n_in,
                              void* d_out, int out_size, void* d_ws, size_t ws_size,
                              hipStream_t stream) {
    const float* x  = (const float*)d_in[0];
    const float* Wq = (const float*)d_in[1];
    const float* Wk = (const float*)d_in[2];
    const float* Wv = (const float*)d_in[3];
    float* out = (float*)d_out;

    char* ws = (char*)d_ws;
    ushort* Wfm = (ushort*)(ws);                 // 384 KB
    ushort* Qfm = (ushort*)(ws + 393216);        // 2 MB
    ushort* Kfm = (ushort*)(ws + 2490368);       // 2 MB
    ushort* Vfm = (ushort*)(ws + 4587520);       // 2 MB
    float*  Op  = (float*) (ws + 6684672);       // 16 MB (4 splits x 4 MB)
    float*  lp  = (float*) (ws + 23461888);      // 256 KB

    wcvt<<<96, 256, 0, stream>>>(Wq, Wk, Wv, Wfm);
    qkv<<<512, 256, 0, stream>>>(x, Wfm, Qfm, Kfm, Vfm);
    flash<<<dim3(32, B_BAT, NSPLIT), 256, 0, stream>>>(Qfm, Kfm, Vfm, Op, lp);
    combine<<<1024, 256, 0, stream>>>(Op, lp, out);
}

// Round 3
// 133.413 us; speedup vs baseline: 1.0483x; 1.0135x over previous
//
#include <hip/hip_runtime.h>
#include <stdint.h>

typedef __bf16 bf16x8 __attribute__((ext_vector_type(8)));
typedef float  f32x4  __attribute__((ext_vector_type(4)));

#define E_DIM 1024
#define H_DIM 64
#define T_SEQ 4096
#define B_BAT 4
#define M_TOT (B_BAT * T_SEQ)   // 16384

// f32 -> bf16 via hardware cvt (RNE, v_cvt_pk_bf16_f32). Compiler pairs casts.
__device__ __forceinline__ ushort f2bfu(float f) {
    return __builtin_bit_cast(ushort, (__bf16)f);
}
// packed fp32x2 -> bf16x2 (RNE, single v_cvt_pk_bf16_f32)
__device__ __forceinline__ uint32_t pk2(float lo, float hi) {
    return (uint32_t)f2bfu(lo) | ((uint32_t)f2bfu(hi) << 16);
}
__device__ __forceinline__ float ex2(float x) {    // 2^x, single trans op
    return __builtin_amdgcn_exp2f(x);
}
__device__ __forceinline__ bf16x8 ldfrag(const ushort* p) {
    return __builtin_bit_cast(bf16x8, *(const uint4*)(p));
}
// barrier that waits LDS only — global prefetch stays in flight (vmcnt not drained)
__device__ __forceinline__ void barrier_lgkm() {
    __builtin_amdgcn_s_waitcnt(0xC07F);   // vmcnt(63) expcnt(7) lgkmcnt(0)
    __builtin_amdgcn_s_barrier();
}

// ---------------- kernel 0: W fp32 -> frag-major bf16 -----------------------
// Wfm[s 16][nt 12][kc 2][lane 64][8]; Wq rows (n<64) pre-scaled by 1/(32*ln2)
// so flash can use exp2 directly (softmax invariant to the log-base change).
__global__ __launch_bounds__(256) void wcvt(const float* __restrict__ Wq,
                                            const float* __restrict__ Wk,
                                            const float* __restrict__ Wv,
                                            ushort* __restrict__ Wfm) {
    int g = blockIdx.x * 256 + threadIdx.x;   // 24576 threads
    int n = g >> 7;          // 0..191
    int k8 = g & 127;
    const float* src = (n < 64) ? (Wq + (size_t)n * E_DIM)
                     : (n < 128) ? (Wk + (size_t)(n - 64) * E_DIM)
                     : (Wv + (size_t)(n - 128) * E_DIM);
    float sc = (n < 64) ? 0.045084220f : 1.0f;   // (1/32) * (1/ln2)
    float4 a = *(const float4*)(src + k8 * 8);
    float4 b = *(const float4*)(src + k8 * 8 + 4);
    uint4 o;
    o.x = pk2(a.x * sc, a.y * sc); o.y = pk2(a.z * sc, a.w * sc);
    o.z = pk2(b.x * sc, b.y * sc); o.w = pk2(b.z * sc, b.w * sc);
    int s = k8 >> 3, kc = (k8 >> 2) & 1, qd = k8 & 3;
    int nt = n >> 4, lm = n & 15;
    int lane = qd * 16 + lm;
    *(uint4*)(Wfm + (((size_t)(s * 12 + nt) * 2 + kc) * 64 + lane) * 8) = o;
}

// ---------------- kernel 1: QKV projection ----------------------------------
// 32-row blocks, BK=64, 16 steps. 3-deep x pipeline (load s+3 / stage s+1 /
// compute s); lgkm-only in-loop barriers keep global loads in flight.
__global__ __launch_bounds__(256, 3) void qkv(const float* __restrict__ x,
                                              const ushort* __restrict__ Wfm,
                                              ushort* __restrict__ Qfm,
                                              ushort* __restrict__ Kfm,
                                              ushort* __restrict__ Vfm) {
    __shared__ union {
        ushort a[2][32 * 72];                              // staging dbuf (9216 B)
        struct { ushort c[32 * 136]; ushort vt[64 * 40]; } epi;  // epilogue (13824 B)
    } sm;
    const int tid = threadIdx.x;
    const int w = tid >> 6, l = tid & 63;
    const int lm = l & 15, qd = l >> 4;
    const int m0 = blockIdx.x * 32;

    f32x4 acc[2][3];
#pragma unroll
    for (int r2 = 0; r2 < 2; ++r2)
#pragma unroll
        for (int t = 0; t < 3; ++t) acc[r2][t] = (f32x4){0.f, 0.f, 0.f, 0.f};

    const int srow = tid >> 3, kseg = tid & 7;
    const float* xsrc = x + (size_t)(m0 + srow) * E_DIM + kseg * 8;

    // tile 0 -> LDS[0]
    {
        float4 a0 = *(const float4*)xsrc;
        float4 a1 = *(const float4*)(xsrc + 4);
        uint4 u = {pk2(a0.x, a0.y), pk2(a0.z, a0.w), pk2(a1.x, a1.y), pk2(a1.z, a1.w)};
        *(uint4*)(&sm.a[0][srow * 72 + kseg * 8]) = u;
    }
    // tiles 1,2 -> regs (3-deep pipeline)
    float4 xa0 = *(const float4*)(xsrc + 64);
    float4 xa1 = *(const float4*)(xsrc + 68);
    float4 xb0 = *(const float4*)(xsrc + 128);
    float4 xb1 = *(const float4*)(xsrc + 132);
    __syncthreads();

    for (int s = 0; s < 16; ++s) {
        const int cb = s & 1, nb = cb ^ 1;
        float4 xc0 = xa0, xc1 = xa1;
        if (s < 13) {                       // load tile s+3
            xc0 = *(const float4*)(xsrc + (s + 3) * 64);
            xc1 = *(const float4*)(xsrc + (s + 3) * 64 + 4);
        }
        // W frags for this step (global, L2-resident, lane-dense)
        bf16x8 wf[3][2];
#pragma unroll
        for (int t = 0; t < 3; ++t)
#pragma unroll
            for (int kc = 0; kc < 2; ++kc)
                wf[t][kc] = ldfrag(Wfm + (((size_t)(s * 12 + w * 3 + t) * 2 + kc) * 64 + l) * 8);
        // A frags from LDS
        bf16x8 af[2][2];
#pragma unroll
        for (int r2 = 0; r2 < 2; ++r2)
#pragma unroll
            for (int kc = 0; kc < 2; ++kc)
                af[r2][kc] = ldfrag(&sm.a[cb][(r2 * 16 + lm) * 72 + kc * 32 + qd * 8]);
#pragma unroll
        for (int t = 0; t < 3; ++t)
#pragma unroll
            for (int kc = 0; kc < 2; ++kc)
#pragma unroll
                for (int r2 = 0; r2 < 2; ++r2)
                    acc[r2][t] = __builtin_amdgcn_mfma_f32_16x16x32_bf16(af[r2][kc], wf[t][kc], acc[r2][t], 0, 0, 0);
        // stage tile s+1 (regs loaded two full steps ago)
        if (s < 15) {
            uint4 u = {pk2(xa0.x, xa0.y), pk2(xa0.z, xa0.w), pk2(xa1.x, xa1.y), pk2(xa1.z, xa1.w)};
            *(uint4*)(&sm.a[nb][srow * 72 + kseg * 8]) = u;
        }
        xa0 = xb0; xa1 = xb1; xb0 = xc0; xb1 = xc1;
        if (s < 15) barrier_lgkm();
    }
    __syncthreads();

    // epilogue: acc -> LDS transpose -> frag-major dense stores
#pragma unroll
    for (int r2 = 0; r2 < 2; ++r2)
#pragma unroll
        for (int t = 0; t < 3; ++t) {
            int gc = w * 48 + t * 16 + lm;
            int m = r2 * 16 + qd * 4;
#pragma unroll
            for (int rr = 0; rr < 4; ++rr) {
                ushort v = f2bfu(acc[r2][t][rr]);
                if (gc < 128) sm.epi.c[(m + rr) * 136 + gc] = v;
                else          sm.epi.vt[(gc - 128) * 40 + (m + rr)] = v;
            }
        }
    __syncthreads();

    const int g16b = m0 >> 4;
    const int kt64 = m0 >> 6;
    const int tb   = (m0 >> 4) & 3;
    const int kcv  = (m0 >> 5) & 1;
#pragma unroll
    for (int ii = 0; ii < 3; ++ii) {
        int i = w + ii * 4;
        uint4 val;
        ushort* dst;
        if (i < 4) {
            int qt_l = i >> 1, kc = i & 1;
            val = *(const uint4*)(&sm.epi.c[(qt_l * 16 + lm) * 136 + kc * 32 + qd * 8]);
            dst = Qfm + (((size_t)(g16b + qt_l) * 2 + kc) * 64 + l) * 8;
        } else if (i < 8) {
            int j2 = i - 4, t_l = j2 >> 1, kc = j2 & 1;
            val = *(const uint4*)(&sm.epi.c[(t_l * 16 + lm) * 136 + 64 + kc * 32 + qd * 8]);
            dst = Kfm + (((size_t)((kt64 * 4 + tb + t_l) * 2 + kc)) * 64 + l) * 8;
        } else {
            int t = i - 8;
            val = *(const uint4*)(&sm.epi.vt[(t * 16 + lm) * 40 + qd * 8]);
            dst = Vfm + (((size_t)((kt64 * 4 + t) * 2 + kcv)) * 64 + l) * 8;
        }
        *(uint4*)dst = val;
    }
}

// ---------------- kernel 2: causal flash attention, fused split-K -----------
// Block = (q-16-row-tile pair j / 255-j, batch). The 4 waves each take key
// split h = wv over the SAME 16 query rows; partial O (16x64) + l reduced
// in LDS at end of each half, final fp32 output written directly.
// Inner loop identical to split-K version; diagonal mask keyed on td = j&3.
__global__ __launch_bounds__(256, 4) void flashc(const ushort* __restrict__ Qfm,
                                                 const ushort* __restrict__ Kfm,
                                                 const ushort* __restrict__ Vfm,
                                                 float* __restrict__ out) {
    __shared__ ushort plds[4][16 * 72];  // wave-private P (stride 72: bank-uniform)
    __shared__ float  ro[4][16][68];     // per-wave partial O tiles (17408 B)
    __shared__ float  rl[4][16];         // per-wave partial l
    const int tid = threadIdx.x;
    const int wv = tid >> 6, l = tid & 63;
    const int lm = l & 15, qd = l >> 4;
    const int pr = blockIdx.x;   // pair 0..127
    const int bt = blockIdx.y;
    ushort* myp = plds[wv];

#pragma unroll 1
    for (int half = 0; half < 2; ++half) {
        const int j   = half ? (255 - pr) : pr;   // q-16-row tile 0..255
        const int ktd = j >> 2;                   // diagonal 64-key tile
        const int td  = j & 3;                    // diagonal 16-key subtile
        const int g16 = bt * 256 + j;

        bf16x8 qf0, qf1;
        {
            const ushort* qp = Qfm + ((size_t)g16 * 2) * 512 + l * 8;
            qf0 = ldfrag(qp);
            qf1 = ldfrag(qp + 512);
        }
        f32x4 o[4];
#pragma unroll
        for (int t = 0; t < 4; ++t) o[t] = (f32x4){0.f, 0.f, 0.f, 0.f};
        float lacc = 0.f;

#pragma unroll 1
        for (int kt = wv; kt <= ktd; kt += 4) {
            const ushort* kb = Kfm + ((size_t)(bt * 64 + kt) * 8) * 512;
            const ushort* vb = Vfm + ((size_t)(bt * 64 + kt) * 8) * 512;
            f32x4 sf[4];
#pragma unroll
            for (int t = 0; t < 4; ++t) sf[t] = (f32x4){0.f, 0.f, 0.f, 0.f};
#pragma unroll
            for (int t = 0; t < 4; ++t) {
                bf16x8 k0 = ldfrag(kb + (t * 2 + 0) * 512 + l * 8);
                bf16x8 k1 = ldfrag(kb + (t * 2 + 1) * 512 + l * 8);
                sf[t] = __builtin_amdgcn_mfma_f32_16x16x32_bf16(k0, qf0, sf[t], 0, 0, 0);
                sf[t] = __builtin_amdgcn_mfma_f32_16x16x32_bf16(k1, qf1, sf[t], 0, 0, 0);
            }
            uint4 vu[4][2];
#pragma unroll
            for (int t = 0; t < 4; ++t) {
                vu[t][0] = *(const uint4*)(vb + (t * 2 + 0) * 512 + l * 8);
                vu[t][1] = *(const uint4*)(vb + (t * 2 + 1) * 512 + l * 8);
            }
            ushort* wp = myp + lm * 72 + qd * 4;
            if (kt != ktd) {           // fully unmasked tile
#pragma unroll
                for (int t = 0; t < 4; ++t) {
                    float p0 = ex2(sf[t][0]), p1 = ex2(sf[t][1]);
                    float p2 = ex2(sf[t][2]), p3 = ex2(sf[t][3]);
                    lacc += (p0 + p1) + (p2 + p3);
                    *(uint2*)(wp + t * 16) = uint2{pk2(p0, p1), pk2(p2, p3)};
                }
            } else {                   // diagonal tile: t<td full, t==td tri, t>td zero
#pragma unroll
                for (int t = 0; t < 4; ++t) {
                    if (t < td) {
                        float p0 = ex2(sf[t][0]), p1 = ex2(sf[t][1]);
                        float p2 = ex2(sf[t][2]), p3 = ex2(sf[t][3]);
                        lacc += (p0 + p1) + (p2 + p3);
                        *(uint2*)(wp + t * 16) = uint2{pk2(p0, p1), pk2(p2, p3)};
                    } else if (t == td) {
                        float p[4];
#pragma unroll
                        for (int rr = 0; rr < 4; ++rr) {
                            float pe = ex2(sf[t][rr]);
                            if (qd * 4 + rr > lm) pe = 0.f;
                            lacc += pe;
                            p[rr] = pe;
                        }
                        *(uint2*)(wp + t * 16) = uint2{pk2(p[0], p[1]), pk2(p[2], p[3])};
                    } else {
                        *(uint2*)(wp + t * 16) = uint2{0u, 0u};
                    }
                }
            }
            __builtin_amdgcn_wave_barrier();
            __builtin_amdgcn_s_waitcnt(0xC07F);  // lgkmcnt(0): P committed (wave-private)
            __builtin_amdgcn_wave_barrier();
            bf16x8 pf0 = ldfrag(myp + lm * 72 + qd * 8);
            bf16x8 pf1 = ldfrag(myp + lm * 72 + 32 + qd * 8);
#pragma unroll
            for (int t = 0; t < 4; ++t) {
                bf16x8 v0 = __builtin_bit_cast(bf16x8, vu[t][0]);
                bf16x8 v1 = __builtin_bit_cast(bf16x8, vu[t][1]);
                o[t] = __builtin_amdgcn_mfma_f32_16x16x32_bf16(pf0, v0, o[t], 0, 0, 0);
                o[t] = __builtin_amdgcn_mfma_f32_16x16x32_bf16(pf1, v1, o[t], 0, 0, 0);
            }
            __builtin_amdgcn_wave_barrier();  // next iter's P writes stay after these reads
        }
        // per-wave l for each query row (all lanes hold it after xor-reduce)
        lacc += __shfl_xor(lacc, 16);
        lacc += __shfl_xor(lacc, 32);
        if (qd == 0) rl[wv][lm] = lacc;
        // partial O tile -> LDS (row stride 68: 2-way bank alias, free)
#pragma unroll
        for (int t = 0; t < 4; ++t)
#pragma unroll
            for (int rr = 0; rr < 4; ++rr)
                ro[wv][qd * 4 + rr][t * 16 + lm] = o[t][rr];
        __syncthreads();
        // cross-wave reduce: wave wv sums rows [4wv, 4wv+4), writes final out
        {
            const int row = wv * 4 + qd;
            float ls = rl[0][row] + rl[1][row] + rl[2][row] + rl[3][row];
            float inv = 1.0f / ls;
            float4 s0 = *(const float4*)&ro[0][row][lm * 4];
            float4 s1 = *(const float4*)&ro[1][row][lm * 4];
            float4 s2 = *(const float4*)&ro[2][row][lm * 4];
            float4 s3 = *(const float4*)&ro[3][row][lm * 4];
            float4 ov;
            ov.x = (s0.x + s1.x + s2.x + s3.x) * inv;
            ov.y = (s0.y + s1.y + s2.y + s3.y) * inv;
            ov.z = (s0.z + s1.z + s2.z + s3.z) * inv;
            ov.w = (s0.w + s1.w + s2.w + s3.w) * inv;
            *(float4*)(out + ((size_t)bt * T_SEQ + j * 16 + row) * 64 + lm * 4) = ov;
        }
        __syncthreads();   // protect ro/rl before next half's writes
    }
}

extern "C" void kernel_launch(void* const* d_in, const int* in_sizes, int n_in,
                              void* d_out, int out_size, void* d_ws, size_t ws_size,
                              hipStream_t stream) {
    const float* x  = (const float*)d_in[0];
    const float* Wq = (const float*)d_in[1];
    const float* Wk = (const float*)d_in[2];
    const float* Wv = (const float*)d_in[3];
    float* out = (float*)d_out;

    char* ws = (char*)d_ws;
    ushort* Wfm = (ushort*)(ws);                 // 384 KB
    ushort* Qfm = (ushort*)(ws + 393216);        // 2 MB
    ushort* Kfm = (ushort*)(ws + 2490368);       // 2 MB
    ushort* Vfm = (ushort*)(ws + 4587520);       // 2 MB

    wcvt<<<96, 256, 0, stream>>>(Wq, Wk, Wv, Wfm);
    qkv<<<512, 256, 0, stream>>>(x, Wfm, Qfm, Kfm, Vfm);
    flashc<<<dim3(128, B_BAT), 256, 0, stream>>>(Qfm, Kfm, Vfm, out);
}